// Round 2
// baseline (605.266 us; speedup 1.0000x reference)
//
#include <hip/hip_runtime.h>

#define EMBED 4096
#define NH 32
#define HD 128
#define BATCH 64
#define KVLEN 4096
#define QKV_N 4352   // EMBED + 2*HD
#define WP 144       // bf16 LDS pitch for GEMM tiles (72 words; conflict-free frag reads)

// attention LDS pitches (bf16 elements)
#define KPB 136      // K tile pitch: b128 frag reads 16B-aligned, near-minimal banking
#define VPB 132      // V tile pitch: ds_read_u16 B-frag -> <=2-way bank aliasing (free)
#define PPB 40       // P tile pitch: b64 writes / b128 reads aligned, ~2-way banking
#define AR_STRIDE (32 * KPB + 32 * VPB + 32 * PPB)   // 9856 shorts per wave arena

typedef __attribute__((ext_vector_type(8))) short bf16x8;
typedef __attribute__((ext_vector_type(4))) float f32x4;

// round-to-nearest-even fp32 -> bf16, packed pair
__device__ __forceinline__ unsigned int pk_bf16(float a, float b) {
  union { float f; unsigned int u; } ua, ub;
  ua.f = a; ub.f = b;
  unsigned int ra = (ua.u + 0x7fffu + ((ua.u >> 16) & 1u)) >> 16;
  unsigned int rb = (ub.u + 0x7fffu + ((ub.u >> 16) & 1u)) >> 16;
  return ra | (rb << 16);
}

// ---------------------------------------------------------------------------
// bf16-MFMA skinny GEMM: out[64 x N] += X[64 x K] @ W[K x N] (+bias on ksplit 0)
// grid = (N/64, 8 ksplits), block = 256 (4 waves). out must be pre-zeroed.
// (unchanged — attention is the bottleneck under test this round)
// ---------------------------------------------------------------------------
__global__ __launch_bounds__(256, 4)
void gemm_mfma(const float* __restrict__ X, const float* __restrict__ W,
               const float* __restrict__ bias, float* __restrict__ out,
               int K, int N) {
  __shared__ __align__(16) short Xs[64 * WP];   // [row][k] bf16
  __shared__ __align__(16) short Ws[64 * WP];   // [col][k] bf16 (transposed)

  const int t = threadIdx.x;
  const int lane = t & 63;
  const int w = t >> 6;              // wave id, wave-uniform
  const int l15 = lane & 15;
  const int q = lane >> 4;           // quad 0..3
  const int n0 = blockIdx.x * 64;
  const int KSP = K >> 3;
  const int ks = blockIdx.y * KSP;

  // staging maps
  const int xrow = t >> 2, xc0 = (t & 3) * 32;   // X: 64 rows x 128 cols / 256 thr
  const int wc = t & 63;                         // W: col within strip
  const int wkg = (t >> 6) * 8;                  // W: k-group base

  f32x4 acc[4];
#pragma unroll
  for (int mt = 0; mt < 4; ++mt) acc[mt] = (f32x4){0.f, 0.f, 0.f, 0.f};

  for (int kc = 0; kc < KSP; kc += 128) {
    // ---- stage X[0:64][ks+kc : +128] -> Xs bf16 ----
    {
      const float* xp = X + (size_t)xrow * K + ks + kc + xc0;
      float4 xv[8];
#pragma unroll
      for (int i = 0; i < 8; ++i) xv[i] = *(const float4*)(xp + 4 * i);
      short* dst = Xs + xrow * WP + xc0;
#pragma unroll
      for (int i = 0; i < 4; ++i) {
        uint4 pkd;
        pkd.x = pk_bf16(xv[2 * i].x, xv[2 * i].y);
        pkd.y = pk_bf16(xv[2 * i].z, xv[2 * i].w);
        pkd.z = pk_bf16(xv[2 * i + 1].x, xv[2 * i + 1].y);
        pkd.w = pk_bf16(xv[2 * i + 1].z, xv[2 * i + 1].w);
        *(uint4*)(dst + 8 * i) = pkd;
      }
    }
    // ---- stage W[ks+kc : +128][n0 : n0+64] -> Ws[col][k] bf16 (transposed) ----
#pragma unroll
    for (int g = 0; g < 4; ++g) {
      const int kk = wkg + g * 32;    // 0..120, step covers all 16 groups of 8
      const float* wp = W + (size_t)(ks + kc + kk) * N + n0 + wc;
      float wv[8];
#pragma unroll
      for (int j = 0; j < 8; ++j) wv[j] = wp[(size_t)j * N];
      uint4 pkd;
      pkd.x = pk_bf16(wv[0], wv[1]);
      pkd.y = pk_bf16(wv[2], wv[3]);
      pkd.z = pk_bf16(wv[4], wv[5]);
      pkd.w = pk_bf16(wv[6], wv[7]);
      *(uint4*)(Ws + wc * WP + kk) = pkd;
    }
    __syncthreads();
    // ---- MFMA: 4 ksteps x 4 m-tiles ----
#pragma unroll
    for (int kstep = 0; kstep < 4; ++kstep) {
      bf16x8 bfr = *(const bf16x8*)(Ws + (w * 16 + l15) * WP + kstep * 32 + q * 8);
#pragma unroll
      for (int mt = 0; mt < 4; ++mt) {
        bf16x8 afr = *(const bf16x8*)(Xs + (mt * 16 + l15) * WP + kstep * 32 + q * 8);
        acc[mt] = __builtin_amdgcn_mfma_f32_16x16x32_bf16(afr, bfr, acc[mt], 0, 0, 0);
      }
    }
    __syncthreads();
  }

  const int col = n0 + w * 16 + l15;
  const float bcol = (blockIdx.y == 0) ? bias[col] : 0.f;
#pragma unroll
  for (int mt = 0; mt < 4; ++mt) {
#pragma unroll
    for (int r = 0; r < 4; ++r) {
      int row = mt * 16 + q * 4 + r;
      atomicAdd(out + (size_t)row * N + col, acc[mt][r] + bcol);
    }
  }
}

// ---------------------------------------------------------------------------
// Fused KV-cache copy + flash attention, MFMA version.
// grid = (64 batches, 8 chunks of 512 positions), block = 256 (4 waves).
// Each wave independently owns 128 positions (4 tiles of 32): no __syncthreads
// in the main loop; per-wave LDS arenas; wave-internal lgkmcnt ordering only.
//
//   QK^T swapped:  S^T[p][h] = mfma(A=K[p][d], B=Q[h][d])  (scale folded in Q)
//       -> per lane: head = col (l15 + 16*ht), 8 positions across regs;
//          row softmax = 7 fmax + shfl_xor(16) + shfl_xor(32).
//   PV:            O[h][d]  = mfma(A=P[h][p] (LDS, b128), B=V[p][d] (8x u16))
//
// Cross-wave combine at block end through an f32 overlay of the dead arenas;
// 8-chunk partial scheme + attn_combine unchanged.
// ---------------------------------------------------------------------------
__global__ __launch_bounds__(256, 2)
void attn_fused(const float* __restrict__ past, const float* __restrict__ qkv,
                const int* __restrict__ keylen, float* __restrict__ out_past,
                float* __restrict__ part_o, float* __restrict__ part_m,
                float* __restrict__ part_l) {
  __shared__ __align__(16) short arena[4 * AR_STRIDE];   // 78848 B
  __shared__ float mL[4][32], lL[4][32];                 // +1 KB

  const int b = blockIdx.x, ch = blockIdx.y;
  const int t = threadIdx.x;
  const int lane = t & 63;
  const int w = t >> 6;
  const int l15 = lane & 15;
  const int q = lane >> 4;
  const int last = keylen[0] - 1;
  const float scale = 0.088388347648318447f;

  short* Ks = arena + w * AR_STRIDE;     // [32][KPB] bf16
  short* Vs = Ks + 32 * KPB;             // [32][VPB] bf16
  short* Ps = Vs + 32 * VPB;             // [32][PPB] bf16

  const float* qrow = qkv + (size_t)b * QKV_N;

  // ---- hoist Q fragments (B-operand): qfr[ht][ks], element j <-> k = ks*32+q*8+j
  bf16x8 qfr[2][4];
#pragma unroll
  for (int ht = 0; ht < 2; ++ht) {
#pragma unroll
    for (int ks = 0; ks < 4; ++ks) {
      const float* qp = qrow + (ht * 16 + l15) * HD + ks * 32 + q * 8;
      float4 x0 = *(const float4*)qp;
      float4 x1 = *(const float4*)(qp + 4);
      union { bf16x8 v; uint4 u; } un;
      un.u.x = pk_bf16(x0.x * scale, x0.y * scale);
      un.u.y = pk_bf16(x0.z * scale, x0.w * scale);
      un.u.z = pk_bf16(x1.x * scale, x1.y * scale);
      un.u.w = pk_bf16(x1.z * scale, x1.w * scale);
      qfr[ht][ks] = un.v;
    }
  }

  f32x4 acc_o[2][8];
#pragma unroll
  for (int mt = 0; mt < 2; ++mt)
#pragma unroll
    for (int nt = 0; nt < 8; ++nt) acc_o[mt][nt] = (f32x4){0.f, 0.f, 0.f, 0.f};

  float m_run[2] = {-1e30f, -1e30f};
  float l_run[2] = {0.f, 0.f};

  const int pw0 = ch * 512 + w * 128;

  for (int it = 0; it < 4; ++it) {
    const int pbase = pw0 + it * 32;

    // ---- stage 32 positions: copy past->out_past + pack K/V to bf16 LDS ----
    // lane covers float4 index c4=lane of one position (256 floats = 64 lanes x4)
#pragma unroll
    for (int g8 = 0; g8 < 4; ++g8) {
      float4 vb[8];
#pragma unroll
      for (int i = 0; i < 8; ++i) {
        int p = pbase + g8 * 8 + i;
        size_t g = ((size_t)b * KVLEN + p) * 256 + (size_t)lane * 4;
        vb[i] = *(const float4*)(past + g);
      }
#pragma unroll
      for (int i = 0; i < 8; ++i) {
        int rr = g8 * 8 + i;
        int p = pbase + rr;
        size_t g = ((size_t)b * KVLEN + p) * 256 + (size_t)lane * 4;
        if (p == last) vb[i] = *(const float4*)(qrow + EMBED + lane * 4);
        *(float4*)(out_past + g) = vb[i];
        uint2 pk;
        pk.x = pk_bf16(vb[i].x, vb[i].y);
        pk.y = pk_bf16(vb[i].z, vb[i].w);
        int c = lane * 4;
        short* dst = (c < 128) ? (Ks + rr * KPB + c) : (Vs + rr * VPB + (c - 128));
        *(uint2*)dst = pk;
      }
    }

    // ---- QK^T (swapped): sacc[pt][ht] = S^T, row p = pt*16+q*4+r, col h = ht*16+l15
    f32x4 sacc[2][2];
#pragma unroll
    for (int ks = 0; ks < 4; ++ks) {
#pragma unroll
      for (int pt = 0; pt < 2; ++pt) {
        bf16x8 kfr = *(const bf16x8*)(Ks + (pt * 16 + l15) * KPB + ks * 32 + q * 8);
#pragma unroll
        for (int ht = 0; ht < 2; ++ht) {
          if (ks == 0) sacc[pt][ht] = (f32x4){0.f, 0.f, 0.f, 0.f};
          sacc[pt][ht] =
              __builtin_amdgcn_mfma_f32_16x16x32_bf16(kfr, qfr[ht][ks], sacc[pt][ht], 0, 0, 0);
        }
      }
    }

    // ---- online softmax: per lane, heads l15 (ht=0) and l15+16 (ht=1) ----
    float alpha[2];
#pragma unroll
    for (int ht = 0; ht < 2; ++ht) {
      float tm = sacc[0][ht][0];
#pragma unroll
      for (int r = 1; r < 4; ++r) tm = fmaxf(tm, sacc[0][ht][r]);
#pragma unroll
      for (int r = 0; r < 4; ++r) tm = fmaxf(tm, sacc[1][ht][r]);
      tm = fmaxf(tm, __shfl_xor(tm, 16));
      tm = fmaxf(tm, __shfl_xor(tm, 32));
      float mn = fmaxf(m_run[ht], tm);
      alpha[ht] = __expf(m_run[ht] - mn);
      m_run[ht] = mn;
      float rs = 0.f;
#pragma unroll
      for (int pt = 0; pt < 2; ++pt) {
#pragma unroll
        for (int r = 0; r < 4; ++r) {
          float e = __expf(sacc[pt][ht][r] - mn);
          sacc[pt][ht][r] = e;
          rs += e;
        }
      }
      rs += __shfl_xor(rs, 16);
      rs += __shfl_xor(rs, 32);
      l_run[ht] = l_run[ht] * alpha[ht] + rs;
    }

    // ---- write P^T -> Ps[h][p] (bf16) ----
#pragma unroll
    for (int ht = 0; ht < 2; ++ht) {
#pragma unroll
      for (int pt = 0; pt < 2; ++pt) {
        uint2 pk;
        pk.x = pk_bf16(sacc[pt][ht][0], sacc[pt][ht][1]);
        pk.y = pk_bf16(sacc[pt][ht][2], sacc[pt][ht][3]);
        *(uint2*)(Ps + (ht * 16 + l15) * PPB + pt * 16 + q * 4) = pk;
      }
    }

    // ---- rescale O: need alpha[h] for h = mt*16 + q*4 + r (held by lane q*4+r)
    float af[2][4];
#pragma unroll
    for (int r = 0; r < 4; ++r) {
      af[0][r] = __shfl(alpha[0], q * 4 + r);
      af[1][r] = __shfl(alpha[1], q * 4 + r);
    }
#pragma unroll
    for (int mt = 0; mt < 2; ++mt)
#pragma unroll
      for (int nt = 0; nt < 8; ++nt)
#pragma unroll
        for (int r = 0; r < 4; ++r) acc_o[mt][nt][r] *= af[mt][r];

    // ---- PV: O[h][d] += P[h][p] * V[p][d] ----
    bf16x8 pfr[2];
#pragma unroll
    for (int mt = 0; mt < 2; ++mt)
      pfr[mt] = *(const bf16x8*)(Ps + (mt * 16 + l15) * PPB + q * 8);
#pragma unroll
    for (int nt = 0; nt < 8; ++nt) {
      bf16x8 vfr;
#pragma unroll
      for (int j = 0; j < 8; ++j) vfr[j] = Vs[(q * 8 + j) * VPB + nt * 16 + l15];
#pragma unroll
      for (int mt = 0; mt < 2; ++mt)
        acc_o[mt][nt] =
            __builtin_amdgcn_mfma_f32_16x16x32_bf16(pfr[mt], vfr, acc_o[mt][nt], 0, 0, 0);
    }
  }

  // ---- cross-wave combine: m/l stats, then O through f32 overlay of arenas ----
  if (lane < 16) {
    mL[w][lane] = m_run[0]; mL[w][lane + 16] = m_run[1];
    lL[w][lane] = l_run[0]; lL[w][lane + 16] = l_run[1];
  }
  __syncthreads();

  float fw[2][4];
#pragma unroll
  for (int mt = 0; mt < 2; ++mt) {
#pragma unroll
    for (int r = 0; r < 4; ++r) {
      int h = mt * 16 + q * 4 + r;
      float mB = fmaxf(fmaxf(mL[0][h], mL[1][h]), fmaxf(mL[2][h], mL[3][h]));
      fw[mt][r] = __expf(mL[w][h] - mB);
    }
  }
  float* ow = (float*)(arena + w * AR_STRIDE);   // [32][132] f32 overlay (16896 B < arena)
#pragma unroll
  for (int mt = 0; mt < 2; ++mt)
#pragma unroll
    for (int nt = 0; nt < 8; ++nt)
#pragma unroll
      for (int r = 0; r < 4; ++r)
        ow[(mt * 16 + q * 4 + r) * 132 + nt * 16 + l15] = acc_o[mt][nt][r] * fw[mt][r];
  __syncthreads();

  float* po = part_o + ((size_t)b * 8 + ch) * (NH * HD);
  for (int e4 = t; e4 < 1024; e4 += 256) {
    int e = e4 * 4;
    int h = e >> 7, d = e & 127;
    int a = h * 132 + d;
    const float* o0 = (const float*)(arena);
    const float* o1 = (const float*)(arena + AR_STRIDE);
    const float* o2 = (const float*)(arena + 2 * AR_STRIDE);
    const float* o3 = (const float*)(arena + 3 * AR_STRIDE);
    float4 s;
    s.x = o0[a + 0] + o1[a + 0] + o2[a + 0] + o3[a + 0];
    s.y = o0[a + 1] + o1[a + 1] + o2[a + 1] + o3[a + 1];
    s.z = o0[a + 2] + o1[a + 2] + o2[a + 2] + o3[a + 2];
    s.w = o0[a + 3] + o1[a + 3] + o2[a + 3] + o3[a + 3];
    *(float4*)(po + e) = s;
  }
  if (t < 32) {
    float mB = fmaxf(fmaxf(mL[0][t], mL[1][t]), fmaxf(mL[2][t], mL[3][t]));
    float lB = lL[0][t] * __expf(mL[0][t] - mB) + lL[1][t] * __expf(mL[1][t] - mB) +
               lL[2][t] * __expf(mL[2][t] - mB) + lL[3][t] * __expf(mL[3][t] - mB);
    part_m[((size_t)b * 8 + ch) * NH + t] = mB;
    part_l[((size_t)b * 8 + ch) * NH + t] = lB;
  }
}

// ---------------------------------------------------------------------------
// Combine 8 chunk-partials per (b, h). grid = (64, 32), block = 128 (= HD).
// ---------------------------------------------------------------------------
__global__ void attn_combine(const float* __restrict__ part_o,
                             const float* __restrict__ part_m,
                             const float* __restrict__ part_l,
                             float* __restrict__ attn) {
  const int b = blockIdx.x, h = blockIdx.y, d = threadIdx.x;
  float mv[8];
  float m = -1e30f;
#pragma unroll
  for (int c = 0; c < 8; ++c) {
    mv[c] = part_m[((size_t)b * 8 + c) * NH + h];
    m = fmaxf(m, mv[c]);
  }
  float l = 0.f, acc = 0.f;
#pragma unroll
  for (int c = 0; c < 8; ++c) {
    float e = __expf(mv[c] - m);
    l += part_l[((size_t)b * 8 + c) * NH + h] * e;
    acc += e * part_o[(((size_t)b * 8 + c) * NH + h) * HD + d];
  }
  attn[(size_t)b * EMBED + h * HD + d] = acc / l;
}

extern "C" void kernel_launch(void* const* d_in, const int* in_sizes, int n_in,
                              void* d_out, int out_size, void* d_ws, size_t ws_size,
                              hipStream_t stream) {
  const float* hidden = (const float*)d_in[0];
  const float* past   = (const float*)d_in[1];
  const float* attn_w = (const float*)d_in[3];
  const float* attn_b = (const float*)d_in[4];
  const float* proj_w = (const float*)d_in[5];
  const float* proj_b = (const float*)d_in[6];
  const int*   keylen = (const int*)d_in[7];

  float* out  = (float*)d_out;
  float* outp = out + (size_t)BATCH * EMBED;

  float* qkv    = (float*)d_ws;
  float* attnb  = qkv    + (size_t)BATCH * QKV_N;
  float* part_o = attnb  + (size_t)BATCH * EMBED;
  float* part_m = part_o + (size_t)BATCH * 8 * NH * HD;
  float* part_l = part_m + (size_t)BATCH * 8 * NH;

  hipMemsetAsync(qkv, 0, (size_t)BATCH * QKV_N * sizeof(float), stream);
  hipMemsetAsync(out, 0, (size_t)BATCH * EMBED * sizeof(float), stream);

  gemm_mfma<<<dim3(QKV_N / 64, 8), 256, 0, stream>>>(hidden, attn_w, attn_b, qkv, EMBED, QKV_N);
  attn_fused<<<dim3(64, 8), 256, 0, stream>>>(past, qkv, keylen, outp, part_o, part_m, part_l);
  attn_combine<<<dim3(64, 32), 128, 0, stream>>>(part_o, part_m, part_l, attnb);
  gemm_mfma<<<dim3(EMBED / 64, 8), 256, 0, stream>>>(attnb, proj_w, proj_b, out, EMBED, EMBED);
}